// Round 1
// baseline (297.680 us; speedup 1.0000x reference)
//
#include <hip/hip_runtime.h>

#define TLEN 100
#define ECN  100
#define CA1N 100
#define CA3N 100
#define BSZ  4096
#define ACTN 2
#define BT   8      // REAL batch rows per block (MFMA M=16; rows 8..15 are pad)

typedef short bf16x8 __attribute__((ext_vector_type(8)));
typedef float f32x4  __attribute__((ext_vector_type(4)));

__device__ __forceinline__ unsigned short f2bf(float f){ // round-half-up bf16
  union { float f; unsigned int u; } c; c.f = f;
  return (unsigned short)((c.u + 0x8000u) >> 16);
}
__device__ __forceinline__ float fsigm(float x){ // 1/(1+exp(-x)), fast rcp
  float e = __expf(-x);
  return __builtin_amdgcn_rcpf(1.0f + e);
}

// ---- kernel 0: drive[t][j] = sum_k exp(-((t-c_k)/5)^2/2) * Wca3ca1[k][j] ----
__global__ void drive_kernel(const float* __restrict__ Wca3ca1, float* __restrict__ drive){
  __shared__ float ca3row[CA3N];
  const int t = blockIdx.x, tid = threadIdx.x;
  if (tid < CA3N){
    float c = (float)tid * (100.0f / 99.0f);   // linspace(0,100,100)
    float d = ((float)t - c) * 0.2f;           // /SIGMA=5
    ca3row[tid] = __expf(-0.5f * d * d);
  }
  __syncthreads();
  if (tid < CA1N){
    float acc = 0.f;
    for (int k = 0; k < CA3N; ++k) acc = fmaf(ca3row[k], Wca3ca1[k*CA1N + tid], acc);
    drive[t*CA1N + tid] = acc;
  }
}

// frag-linear bf16 A-shadow: element (m,k) lives at
//   ks*512 + (m + 16*((k>>3)&3))*8 + (k&7)   [shorts], ks = k>>5
// so a wave's ds_read_b128 at (ks*1024 + lane*16) bytes is lane-contiguous.
//
// BT=8: grid = 512 blocks -> 2 independent blocks per CU. MFMA M stays 16;
// rows 8..15 are pad (bounded junk: contraction + sigmoid keep them finite).
// All global stores are predicated to q<2 (rows 0..7) so pad rows never
// touch memory owned by the neighboring block.

__global__ __launch_bounds__(512, 4)
void rnn_kernel(const int*   __restrict__ cue_train,
                const float* __restrict__ ec3_last,
                const float* __restrict__ ec5_last,
                const float* __restrict__ cueL,
                const float* __restrict__ cueR,
                const float* __restrict__ Wec3ca1,
                const float* __restrict__ Wca1ec5,
                const float* __restrict__ Wca1act,
                const float* __restrict__ ca1bias,
                const float* __restrict__ drive,
                float*       __restrict__ out)
{
  __shared__ __align__(16) unsigned short ec3b[4 * 64 * 8]; // frag-linear bf16 ec3
  __shared__ __align__(16) unsigned short ca1b[4 * 64 * 8]; // frag-linear bf16 ca1
  __shared__ __align__(16) float ca1f[BT * 132];            // final ca1 (epilogue)
  __shared__ signed char cueT[TLEN * BT];                   // cue transposed [t][r]

  const int tid = threadIdx.x;
  const int b0  = blockIdx.x * BT;

  float* out_act = out;
  float* out_his = out + (size_t)BSZ * ACTN;
  float* out_e3  = out_his + (size_t)TLEN * BSZ * CA1N;
  float* out_e5  = out_e3 + (size_t)BSZ * ECN;
  float* out_c1  = out_e5 + (size_t)BSZ * ECN;

  // --- zero frag shadows (pad K-rows >=100 must stay 0 forever) ---
  for (int idx = tid; idx < 4 * 64 * 8; idx += 512){ ec3b[idx] = 0; ca1b[idx] = 0; }
  // --- stage cue (rows 0..BT-1 only) ---
  for (int idx = tid; idx < BT * TLEN; idx += 512){
    int t = idx >> 3, r = idx & 7;
    cueT[idx] = (signed char)cue_train[(size_t)(b0 + r) * TLEN + t];
  }

  const int lane  = tid & 63;
  const int wv    = tid >> 6;          // wave id = N-tile id (0..7)
  const int col16 = lane & 15;
  const int q     = lane >> 4;         // quad; quads 2,3 hold pad rows 8..15
  const int col   = wv * 16 + col16;   // output column (CA1 ph1 / EC ph2)
  const bool okc  = (col < CA1N);
  const bool wactive = (wv < 7);       // wave 7: cols 112..127 all dead
  const bool realr = okc && (q < 2);   // lane owns real batch rows
  const int colc  = okc ? col : 0;

  // per-lane frag-write base (shorts): same formula for ec3 (k=col) and ca1 (k=col)
  const int abase = (col >> 5) * 512 + ((col >> 3) & 3) * 128 + (col & 7) + q * 32;

  // --- B-fragments in registers (bf16 weights) ---
  bf16x8 b1[4], b2[4];                 // B[k][n]: n=lane&15, k=ks*32+q*8+jj
  #pragma unroll
  for (int ks = 0; ks < 4; ++ks){
    #pragma unroll
    for (int jj = 0; jj < 8; ++jj){
      int k = ks * 32 + q * 8 + jj;
      float w1 = 0.f, w2 = 0.f;
      if (k < ECN && okc){
        w1 = Wec3ca1[k * CA1N + col];
        w2 = Wca1ec5[k * ECN  + col];
      }
      b1[ks][jj] = (short)f2bf(w1);
      b2[ks][jj] = (short)f2bf(w2);
    }
  }
  const float bias_c = okc ? ca1bias[col] : 0.f;
  const float cL = okc ? cueL[col] : 0.f;
  const float cR = okc ? cueR[col] : 0.f;

  __syncthreads();  // frag zero complete before state writes

  // --- fp32 state in registers (lane owns (r=q*4+i, col)); pad rows start 0 ---
  float ec3v[4], ec5v[4], c1[4] = {0.f,0.f,0.f,0.f};
  #pragma unroll
  for (int i = 0; i < 4; ++i){
    int r = q * 4 + i;
    float v3 = realr ? ec3_last[(size_t)(b0 + r) * ECN + col] : 0.f;
    float v5 = realr ? ec5_last[(size_t)(b0 + r) * ECN + col] : 0.f;
    ec3v[i] = v3; ec5v[i] = v5;
    if (okc) ec3b[abase + i * 8] = f2bf(v3);
  }
  __syncthreads();

  // running pointers
  const float* dp = drive + colc;                                   // += CA1N per step
  float* hp = out_his + (size_t)(b0 + q * 4) * CA1N + colc;         // += BSZ*CA1N per step

  const bf16x8* fe3 = (const bf16x8*)ec3b;   // chunk ks at index ks*64+lane
  const bf16x8* fc1 = (const bf16x8*)ca1b;

  for (int t = 0; t < TLEN; ++t){
    float dv  = *dp; dp += CA1N;                               // global, L2-hot
    // pad quads (q>=2) read quad q&1's cue word: bounded junk, no divergence
    int   cu4 = *(const int*)(cueT + t * BT + (q & 1) * 4);

    // ---- phase 1: z = ec3 @ W1 ; ca1 = relu(dv*(1+sig(z)) - bias) ----
    if (wactive){
      f32x4 aA = {0.f,0.f,0.f,0.f}, aB = {0.f,0.f,0.f,0.f};
      bf16x8 a0 = fe3[  0 + lane];
      bf16x8 a1 = fe3[ 64 + lane];
      bf16x8 a2 = fe3[128 + lane];
      bf16x8 a3 = fe3[192 + lane];
      aA = __builtin_amdgcn_mfma_f32_16x16x32_bf16(a0, b1[0], aA, 0, 0, 0);
      aB = __builtin_amdgcn_mfma_f32_16x16x32_bf16(a1, b1[1], aB, 0, 0, 0);
      aA = __builtin_amdgcn_mfma_f32_16x16x32_bf16(a2, b1[2], aA, 0, 0, 0);
      aB = __builtin_amdgcn_mfma_f32_16x16x32_bf16(a3, b1[3], aB, 0, 0, 0);
      f32x4 z = aA + aB;
      float dmb = dv - bias_c;
      #pragma unroll
      for (int i = 0; i < 4; ++i){
        float v = fmaxf(fmaf(dv, fsigm(z[i]), dmb), 0.f);
        c1[i] = v;
        if (okc) ca1b[abase + i * 8] = f2bf(v);
      }
    }
    __syncthreads();

    // out_his stores AFTER the barrier: they drain under phase-2 compute,
    // so the phase-2 barrier's vmcnt(0) is nearly free. Real rows only.
    if (realr){
      hp[0 * CA1N] = c1[0];
      hp[1 * CA1N] = c1[1];
      hp[2 * CA1N] = c1[2];
      hp[3 * CA1N] = c1[3];
    }
    hp += (size_t)BSZ * CA1N;

    // ---- phase 2: z2 = ca1 @ W2 ; ec5/ec3 register update ----
    if (wactive){
      f32x4 aA = {0.f,0.f,0.f,0.f}, aB = {0.f,0.f,0.f,0.f};
      bf16x8 a0 = fc1[  0 + lane];
      bf16x8 a1 = fc1[ 64 + lane];
      bf16x8 a2 = fc1[128 + lane];
      bf16x8 a3 = fc1[192 + lane];
      aA = __builtin_amdgcn_mfma_f32_16x16x32_bf16(a0, b2[0], aA, 0, 0, 0);
      aB = __builtin_amdgcn_mfma_f32_16x16x32_bf16(a1, b2[1], aB, 0, 0, 0);
      aA = __builtin_amdgcn_mfma_f32_16x16x32_bf16(a2, b2[2], aA, 0, 0, 0);
      aB = __builtin_amdgcn_mfma_f32_16x16x32_bf16(a3, b2[3], aB, 0, 0, 0);
      f32x4 z2 = aA + aB;
      #pragma unroll
      for (int i = 0; i < 4; ++i){
        float x  = ec5v[i] + z2[i];
        float e5 = fmaf(0.3f, fsigm(fmaf(4.0f, x, -1.2f)), 0.69f);
        ec5v[i] = e5;
        int cu = (cu4 >> (8 * i)) & 0xff;                 // -1 -> 0xff
        float sns = (cu == 1) ? cL : ((cu == 0xff) ? cR : 0.0f);
        float e3 = fmaf(e5, ec3v[i], sns);
        ec3v[i] = e3;
        if (okc) ec3b[abase + i * 8] = f2bf(e3);
      }
    }
    __syncthreads();
  }

  // ---- epilogue: dump final states from registers (real rows only) ----
  if (realr){
    #pragma unroll
    for (int i = 0; i < 4; ++i){
      int r = q * 4 + i;
      size_t g = (size_t)(b0 + r) * ECN + col;
      out_e3[g] = ec3v[i];
      out_e5[g] = ec5v[i];
      out_c1[g] = c1[i];
      ca1f[r * 132 + col] = c1[i];
    }
  }
  __syncthreads();

  // actCell = ca1_final @ Wca1act
  if (tid < BT * ACTN){
    int r = tid >> 1, a = tid & 1;
    float acc = 0.f;
    for (int jj = 0; jj < CA1N; ++jj)
      acc = fmaf(ca1f[r * 132 + jj], Wca1act[jj * ACTN + a], acc);
    out_act[(size_t)(b0 + r) * ACTN + a] = acc;
  }
}

extern "C" void kernel_launch(void* const* d_in, const int* in_sizes, int n_in,
                              void* d_out, int out_size, void* d_ws, size_t ws_size,
                              hipStream_t stream) {
  (void)in_sizes; (void)n_in; (void)out_size; (void)ws_size;
  const int*   cue_train = (const int*)  d_in[1];
  const float* ec3_last  = (const float*)d_in[2];
  const float* ec5_last  = (const float*)d_in[3];
  const float* cueL      = (const float*)d_in[5];
  const float* cueR      = (const float*)d_in[6];
  const float* Wec3ca1   = (const float*)d_in[7];
  const float* Wca3ca1   = (const float*)d_in[8];
  const float* Wca1ec5   = (const float*)d_in[9];
  const float* Wca1act   = (const float*)d_in[10];
  const float* ca1bias   = (const float*)d_in[11];
  float* out   = (float*)d_out;
  float* drive = (float*)d_ws;   // 100*100 fp32 = 40 KB scratch

  drive_kernel<<<TLEN, 128, 0, stream>>>(Wca3ca1, drive);
  rnn_kernel<<<BSZ / BT, 512, 0, stream>>>(cue_train, ec3_last, ec5_last,
                                           cueL, cueR, Wec3ca1, Wca1ec5,
                                           Wca1act, ca1bias, drive, out);
}

// Round 2
// 270.095 us; speedup vs baseline: 1.1021x; 1.1021x over previous
//
#include <hip/hip_runtime.h>

#define TLEN 100
#define ECN  100
#define CA1N 100
#define CA3N 100
#define BSZ  4096
#define ACTN 2
#define BT   16     // batch rows per block (= MFMA M)

typedef short bf16x8 __attribute__((ext_vector_type(8)));
typedef float f32x4  __attribute__((ext_vector_type(4)));

__device__ __forceinline__ unsigned short f2bf(float f){ // round-half-up bf16
  union { float f; unsigned int u; } c; c.f = f;
  return (unsigned short)((c.u + 0x8000u) >> 16);
}
__device__ __forceinline__ float fsigm(float x){ // 1/(1+exp(-x)), fast rcp
  float e = __expf(-x);
  return __builtin_amdgcn_rcpf(1.0f + e);
}

// Barrier with LDS-only drain: correctness here needs only ca1b/ec3b (LDS)
// ordering across waves. Global stores (out_his) and the drive load need NO
// cross-wave ordering -> let them float across the barrier instead of the
// ~500-1000cy store-ack drain __syncthreads' vmcnt(0) would impose.
// Compiler still auto-inserts vmcnt waits for its own register hazards.
#define BAR_LGKM() asm volatile("s_waitcnt lgkmcnt(0)\n\ts_barrier" ::: "memory")

// ---- kernel 0: drive[t][j] = sum_k exp(-((t-c_k)/5)^2/2) * Wca3ca1[k][j] ----
__global__ void drive_kernel(const float* __restrict__ Wca3ca1, float* __restrict__ drive){
  __shared__ float ca3row[CA3N];
  const int t = blockIdx.x, tid = threadIdx.x;
  if (tid < CA3N){
    float c = (float)tid * (100.0f / 99.0f);   // linspace(0,100,100)
    float d = ((float)t - c) * 0.2f;           // /SIGMA=5
    ca3row[tid] = __expf(-0.5f * d * d);
  }
  __syncthreads();
  if (tid < CA1N){
    float acc = 0.f;
    for (int k = 0; k < CA3N; ++k) acc = fmaf(ca3row[k], Wca3ca1[k*CA1N + tid], acc);
    drive[t*CA1N + tid] = acc;
  }
}

// frag-linear bf16 A-shadow: element (m,k) lives at
//   ks*512 + (m + 16*((k>>3)&3))*8 + (k&7)   [shorts], ks = k>>5
// so a wave's ds_read_b128 at (ks*1024 + lane*16) bytes is lane-contiguous.

__global__ __launch_bounds__(512, 2)
void rnn_kernel(const int*   __restrict__ cue_train,
                const float* __restrict__ ec3_last,
                const float* __restrict__ ec5_last,
                const float* __restrict__ cueL,
                const float* __restrict__ cueR,
                const float* __restrict__ Wec3ca1,
                const float* __restrict__ Wca1ec5,
                const float* __restrict__ Wca1act,
                const float* __restrict__ ca1bias,
                const float* __restrict__ drive,
                float*       __restrict__ out)
{
  __shared__ __align__(16) unsigned short ec3b[4 * 64 * 8]; // frag-linear bf16 ec3
  __shared__ __align__(16) unsigned short ca1b[4 * 64 * 8]; // frag-linear bf16 ca1
  __shared__ __align__(16) float ca1f[BT * 132];            // final ca1 (epilogue)
  __shared__ signed char cueT[TLEN * BT];                   // cue transposed [t][r]

  const int tid = threadIdx.x;
  const int b0  = blockIdx.x * BT;

  float* out_act = out;
  float* out_his = out + (size_t)BSZ * ACTN;
  float* out_e3  = out_his + (size_t)TLEN * BSZ * CA1N;
  float* out_e5  = out_e3 + (size_t)BSZ * ECN;
  float* out_c1  = out_e5 + (size_t)BSZ * ECN;

  // --- zero frag shadows (pad rows k>=100 must stay 0 forever) ---
  for (int idx = tid; idx < 4 * 64 * 8; idx += 512){ ec3b[idx] = 0; ca1b[idx] = 0; }
  // --- stage cue ---
  for (int idx = tid; idx < BT * TLEN; idx += 512){
    int t = idx >> 4, r = idx & 15;
    cueT[idx] = (signed char)cue_train[(size_t)(b0 + r) * TLEN + t];
  }

  const int lane  = tid & 63;
  const int wv    = tid >> 6;          // wave id = N-tile id (0..7)
  const int col16 = lane & 15;
  const int q     = lane >> 4;         // quad
  const int col   = wv * 16 + col16;   // output column (CA1 ph1 / EC ph2)
  const bool okc  = (col < CA1N);
  const bool wactive = (wv < 7);       // wave 7: cols 112..127 all dead
  const int colc  = okc ? col : 0;

  // per-lane frag-write base (shorts): same formula for ec3 (k=col) and ca1 (k=col)
  const int abase = (col >> 5) * 512 + ((col >> 3) & 3) * 128 + (col & 7) + q * 32;

  // --- B-fragments in registers (bf16 weights) ---
  bf16x8 b1[4], b2[4];                 // B[k][n]: n=lane&15, k=ks*32+q*8+jj
  #pragma unroll
  for (int ks = 0; ks < 4; ++ks){
    #pragma unroll
    for (int jj = 0; jj < 8; ++jj){
      int k = ks * 32 + q * 8 + jj;
      float w1 = 0.f, w2 = 0.f;
      if (k < ECN && okc){
        w1 = Wec3ca1[k * CA1N + col];
        w2 = Wca1ec5[k * ECN  + col];
      }
      b1[ks][jj] = (short)f2bf(w1);
      b2[ks][jj] = (short)f2bf(w2);
    }
  }
  const float bias_c = okc ? ca1bias[col] : 0.f;
  const float cL = okc ? cueL[col] : 0.f;
  const float cR = okc ? cueR[col] : 0.f;

  __syncthreads();  // frag zero complete before state writes

  // --- fp32 state in registers (lane owns (r=q*4+i, col) — never shared) ---
  float ec3v[4], ec5v[4], c1[4] = {0.f,0.f,0.f,0.f};
  #pragma unroll
  for (int i = 0; i < 4; ++i){
    int r = q * 4 + i;
    float v3 = okc ? ec3_last[(size_t)(b0 + r) * ECN + col] : 0.f;
    float v5 = okc ? ec5_last[(size_t)(b0 + r) * ECN + col] : 0.f;
    ec3v[i] = v3; ec5v[i] = v5;
    if (okc) ec3b[abase + i * 8] = f2bf(v3);
  }
  __syncthreads();

  // running pointers
  const float* dp = drive + colc;                                   // += CA1N per step
  float* hp = out_his + (size_t)(b0 + q * 4) * CA1N + colc;         // += BSZ*CA1N per step

  const bf16x8* fe3 = (const bf16x8*)ec3b;   // chunk ks at index ks*64+lane
  const bf16x8* fc1 = (const bf16x8*)ca1b;

  float dv = *dp;                       // prefetched drive value for step t

  for (int t = 0; t < TLEN; ++t){
    int cu4 = *(const int*)(cueT + t * BT + q * 4);            // 4 cue bytes (rows q*4..)

    // ---- phase 1: z = ec3 @ W1 ; ca1 = relu(dv*(1+sig(z)) - bias) ----
    if (wactive){
      f32x4 aA = {0.f,0.f,0.f,0.f}, aB = {0.f,0.f,0.f,0.f};
      bf16x8 a0 = fe3[  0 + lane];
      bf16x8 a1 = fe3[ 64 + lane];
      bf16x8 a2 = fe3[128 + lane];
      bf16x8 a3 = fe3[192 + lane];
      aA = __builtin_amdgcn_mfma_f32_16x16x32_bf16(a0, b1[0], aA, 0, 0, 0);
      aB = __builtin_amdgcn_mfma_f32_16x16x32_bf16(a1, b1[1], aB, 0, 0, 0);
      aA = __builtin_amdgcn_mfma_f32_16x16x32_bf16(a2, b1[2], aA, 0, 0, 0);
      aB = __builtin_amdgcn_mfma_f32_16x16x32_bf16(a3, b1[3], aB, 0, 0, 0);
      f32x4 z = aA + aB;
      float dmb = dv - bias_c;
      #pragma unroll
      for (int i = 0; i < 4; ++i){
        float v = fmaxf(fmaf(dv, fsigm(z[i]), dmb), 0.f);
        c1[i] = v;
        if (okc) ca1b[abase + i * 8] = f2bf(v);
      }
    }
    BAR_LGKM();

    // out_his stores after the barrier: with no vmcnt drain at the loop
    // barriers they stay in flight under phase-2 compute and beyond.
    if (okc){
      hp[0 * CA1N] = c1[0];
      hp[1 * CA1N] = c1[1];
      hp[2 * CA1N] = c1[2];
      hp[3 * CA1N] = c1[3];
    }
    hp += (size_t)BSZ * CA1N;

    // prefetch next step's drive value (floats across the phase-2 barrier)
    dp += CA1N;
    float dv_next = (t + 1 < TLEN) ? *dp : 0.f;

    // ---- phase 2: z2 = ca1 @ W2 ; ec5/ec3 register update ----
    if (wactive){
      f32x4 aA = {0.f,0.f,0.f,0.f}, aB = {0.f,0.f,0.f,0.f};
      bf16x8 a0 = fc1[  0 + lane];
      bf16x8 a1 = fc1[ 64 + lane];
      bf16x8 a2 = fc1[128 + lane];
      bf16x8 a3 = fc1[192 + lane];
      aA = __builtin_amdgcn_mfma_f32_16x16x32_bf16(a0, b2[0], aA, 0, 0, 0);
      aB = __builtin_amdgcn_mfma_f32_16x16x32_bf16(a1, b2[1], aB, 0, 0, 0);
      aA = __builtin_amdgcn_mfma_f32_16x16x32_bf16(a2, b2[2], aA, 0, 0, 0);
      aB = __builtin_amdgcn_mfma_f32_16x16x32_bf16(a3, b2[3], aB, 0, 0, 0);
      f32x4 z2 = aA + aB;
      #pragma unroll
      for (int i = 0; i < 4; ++i){
        float x  = ec5v[i] + z2[i];
        float e5 = fmaf(0.3f, fsigm(fmaf(4.0f, x, -1.2f)), 0.69f);
        ec5v[i] = e5;
        int cu = (cu4 >> (8 * i)) & 0xff;                 // -1 -> 0xff
        float sns = (cu == 1) ? cL : ((cu == 0xff) ? cR : 0.0f);
        float e3 = fmaf(e5, ec3v[i], sns);
        ec3v[i] = e3;
        if (okc) ec3b[abase + i * 8] = f2bf(e3);
      }
    }
    BAR_LGKM();
    dv = dv_next;
  }

  // ---- epilogue: dump final states from registers ----
  if (okc){
    #pragma unroll
    for (int i = 0; i < 4; ++i){
      int r = q * 4 + i;
      size_t g = (size_t)(b0 + r) * ECN + col;
      out_e3[g] = ec3v[i];
      out_e5[g] = ec5v[i];
      out_c1[g] = c1[i];
      ca1f[r * 132 + col] = c1[i];
    }
  }
  __syncthreads();

  // actCell = ca1_final @ Wca1act
  if (tid < BT * ACTN){
    int r = tid >> 1, a = tid & 1;
    float acc = 0.f;
    for (int jj = 0; jj < CA1N; ++jj)
      acc = fmaf(ca1f[r * 132 + jj], Wca1act[jj * ACTN + a], acc);
    out_act[(size_t)(b0 + r) * ACTN + a] = acc;
  }
}

extern "C" void kernel_launch(void* const* d_in, const int* in_sizes, int n_in,
                              void* d_out, int out_size, void* d_ws, size_t ws_size,
                              hipStream_t stream) {
  (void)in_sizes; (void)n_in; (void)out_size; (void)ws_size;
  const int*   cue_train = (const int*)  d_in[1];
  const float* ec3_last  = (const float*)d_in[2];
  const float* ec5_last  = (const float*)d_in[3];
  const float* cueL      = (const float*)d_in[5];
  const float* cueR      = (const float*)d_in[6];
  const float* Wec3ca1   = (const float*)d_in[7];
  const float* Wca3ca1   = (const float*)d_in[8];
  const float* Wca1ec5   = (const float*)d_in[9];
  const float* Wca1act   = (const float*)d_in[10];
  const float* ca1bias   = (const float*)d_in[11];
  float* out   = (float*)d_out;
  float* drive = (float*)d_ws;   // 100*100 fp32 = 40 KB scratch

  drive_kernel<<<TLEN, 128, 0, stream>>>(Wca3ca1, drive);
  rnn_kernel<<<BSZ / BT, 512, 0, stream>>>(cue_train, ec3_last, ec5_last,
                                           cueL, cueR, Wec3ca1, Wca1ec5,
                                           Wca1act, ca1bias, drive, out);
}